// Round 1
// baseline (600.656 us; speedup 1.0000x reference)
//
#include <hip/hip_runtime.h>
#include <cstdint>
#include <cstddef>

typedef __bf16 bf16;
typedef bf16 bf16x4 __attribute__((ext_vector_type(4)));
typedef bf16 bf16x8 __attribute__((ext_vector_type(8)));
typedef float f32x4 __attribute__((ext_vector_type(4)));

// ---------------- graph preprocessing ----------------
__global__ void k_init(int* __restrict__ deg, int* __restrict__ cur,
                       float* __restrict__ sums1, float* __restrict__ sums2, int N) {
  int i = blockIdx.x * 256 + threadIdx.x;
  if (i < N) { deg[i] = 1; cur[i] = 0; }   // deg starts at 1: self loop
  if (i < 512)  sums1[i] = 0.f;
  if (i < 1024) sums2[i] = 0.f;
}

__global__ void k_count(const int* __restrict__ ei, int* __restrict__ deg, int E) {
  int e = blockIdx.x * 256 + threadIdx.x;
  if (e < E) atomicAdd(&deg[ei[E + e]], 1);   // dst = ei[E+e]
}

__global__ __launch_bounds__(1024) void k_scan(const int* __restrict__ deg,
                                               int* __restrict__ roff, int N) {
  __shared__ int part[1024];
  int t = threadIdx.x;
  int chunk = (N + 1023) >> 10;
  int lo = t * chunk, hi = min(lo + chunk, N);
  int s = 0;
  for (int i = lo; i < hi; ++i) s += deg[i] - 1;   // edge-only counts
  part[t] = s;
  __syncthreads();
  for (int off = 1; off < 1024; off <<= 1) {
    int add = (t >= off) ? part[t - off] : 0;
    __syncthreads();
    part[t] += add;
    __syncthreads();
  }
  int run = (t > 0) ? part[t - 1] : 0;
  for (int i = lo; i < hi; ++i) { roff[i] = run; run += deg[i] - 1; }
  if (t == 1023) roff[N] = part[1023];
}

__global__ void k_dinv(const int* __restrict__ deg, float* __restrict__ dinv, int N) {
  int i = blockIdx.x * 256 + threadIdx.x;
  if (i < N) dinv[i] = rsqrtf((float)deg[i]);
}

__global__ void k_scatter(const int* __restrict__ ei, const int* __restrict__ roff,
                          int* __restrict__ cur, int* __restrict__ csr, int E) {
  int e = blockIdx.x * 256 + threadIdx.x;
  if (e >= E) return;
  int d = ei[E + e];
  int p = atomicAdd(&cur[d], 1);
  csr[roff[d] + p] = ei[e];   // src
}

// ---------------- dtype conversion ----------------
__global__ void k_cvt_x(const float* __restrict__ x, bf16* __restrict__ xb,
                        int Nreal, int D, size_t total) {
  size_t base = ((size_t)blockIdx.x * 256 + threadIdx.x) * 4;
  if (base >= total) return;
  int row = (int)(base / D);
  bf16x4 o;
  if (row < Nreal) {
    const float4 v = *(const float4*)(x + base);
    o[0] = (bf16)v.x; o[1] = (bf16)v.y; o[2] = (bf16)v.z; o[3] = (bf16)v.w;
  } else {
    o[0] = o[1] = o[2] = o[3] = (bf16)0.f;   // zero pad rows
  }
  *(bf16x4*)(xb + base) = o;
}

__global__ void k_cvt_wt(const float* __restrict__ W, bf16* __restrict__ Wt,
                         int K, int Nout) {
  int i = blockIdx.x * 256 + threadIdx.x;
  if (i >= K * Nout) return;
  int n = i / K, k = i - n * K;
  Wt[i] = (bf16)W[(size_t)k * Nout + n];   // Wt[n][k] = W[k][n]
}

// ---------------- bf16 MFMA GEMM: C[M,NOUT] = A[M,K] @ Bt[NOUT,K]^T ----------------
// 128x128 tile, BK=32, 4 waves each computing a 64x64 quadrant as 4x4 16x16 tiles.
// LDS layout: 16B slot s = kblock*128 + row  -> conflict-free ds_read_b128 frags.
template<int K, int NOUT, bool FINAL>
__global__ __launch_bounds__(256) void k_gemm(const bf16* __restrict__ A,
                                              const bf16* __restrict__ Bt,
                                              bf16* __restrict__ outB,
                                              float* __restrict__ outF,
                                              const float* __restrict__ bias,
                                              int Mreal) {
  __shared__ uint4 lA[512];
  __shared__ uint4 lB[512];
  const int tid = threadIdx.x;
  const int wv = tid >> 6, lane = tid & 63;
  const int q = lane >> 4, mr = lane & 15;
  const int m0 = blockIdx.x * 128;
  const int n0 = blockIdx.y * 128;
  const int rw = (wv >> 1) * 64, cw = (wv & 1) * 64;
  f32x4 acc[4][4];
#pragma unroll
  for (int r = 0; r < 4; ++r)
#pragma unroll
    for (int c = 0; c < 4; ++c) acc[r][c] = (f32x4){0.f, 0.f, 0.f, 0.f};

  for (int k0 = 0; k0 < K; k0 += 32) {
    __syncthreads();
#pragma unroll
    for (int it = 0; it < 2; ++it) {
      int s = it * 256 + tid;
      int row = s & 127, kb = s >> 7;
      lA[s] = *(const uint4*)(A + (size_t)(m0 + row) * K + (k0 + kb * 8));
      lB[s] = *(const uint4*)(Bt + (size_t)(n0 + row) * K + (k0 + kb * 8));
    }
    __syncthreads();
    bf16x8 af[4], bfr[4];
#pragma unroll
    for (int r = 0; r < 4; ++r)
      af[r] = ((const bf16x8*)lA)[q * 128 + rw + r * 16 + mr];
#pragma unroll
    for (int c = 0; c < 4; ++c)
      bfr[c] = ((const bf16x8*)lB)[q * 128 + cw + c * 16 + mr];
#pragma unroll
    for (int r = 0; r < 4; ++r)
#pragma unroll
      for (int c = 0; c < 4; ++c)
        acc[r][c] = __builtin_amdgcn_mfma_f32_16x16x32_bf16(af[r], bfr[c], acc[r][c], 0, 0, 0);
  }

  // C/D layout: col = lane&15, row = (lane>>4)*4 + reg (m89/m91-verified)
#pragma unroll
  for (int r = 0; r < 4; ++r) {
#pragma unroll
    for (int c = 0; c < 4; ++c) {
#pragma unroll
      for (int i = 0; i < 4; ++i) {
        int row = m0 + rw + r * 16 + q * 4 + i;
        int col = n0 + cw + c * 16 + mr;
        if (FINAL) {
          if (row < Mreal) outF[(size_t)row * NOUT + col] = acc[r][c][i] + bias[col];
        } else {
          outB[(size_t)row * NOUT + col] = (bf16)acc[r][c][i];
        }
      }
    }
  }
}

// ---------------- CSR aggregation: g[v] = dinv[v]*(sum_e dinv[s]*h[s]) + dinv[v]^2*h[v] ----------------
template<int C>
__global__ __launch_bounds__(256) void k_agg(const bf16* __restrict__ h,
                                             bf16* __restrict__ g,
                                             const int* __restrict__ csr,
                                             const int* __restrict__ roff,
                                             const float* __restrict__ dinv, int N) {
  constexpr int VPL = C / 64;   // channels per lane: 4 or 8
  const int lane = threadIdx.x & 63;
  const int v = (int)(((size_t)blockIdx.x * 256 + threadIdx.x) >> 6);
  if (v >= N) return;
  const float dv = dinv[v];
  float acc[VPL];
  {
    const bf16* hv = h + (size_t)v * C + lane * VPL;
    if constexpr (VPL == 4) {
      bf16x4 t = *(const bf16x4*)hv;
#pragma unroll
      for (int j = 0; j < 4; ++j) acc[j] = dv * (float)t[j];   // self loop: *dv^2 (second dv at end)
    } else {
      bf16x8 t = *(const bf16x8*)hv;
#pragma unroll
      for (int j = 0; j < 8; ++j) acc[j] = dv * (float)t[j];
    }
  }
  const int beg = roff[v], end = roff[v + 1];
  for (int base = beg; base < end; base += 64) {
    int cnt = min(64, end - base);
    int s = 0; float w = 0.f;
    if (lane < cnt) { s = csr[base + lane]; w = dinv[s]; }
    for (int j = 0; j < cnt; ++j) {
      int sj = __shfl(s, j, 64);
      float wj = __shfl(w, j, 64);
      const bf16* hr = h + (size_t)sj * C + lane * VPL;
      if constexpr (VPL == 4) {
        bf16x4 t = *(const bf16x4*)hr;
#pragma unroll
        for (int u = 0; u < 4; ++u) acc[u] += wj * (float)t[u];
      } else {
        bf16x8 t = *(const bf16x8*)hr;
#pragma unroll
        for (int u = 0; u < 8; ++u) acc[u] += wj * (float)t[u];
      }
    }
  }
  bf16* gv = g + (size_t)v * C + lane * VPL;
  if constexpr (VPL == 4) {
    bf16x4 o;
#pragma unroll
    for (int j = 0; j < 4; ++j) o[j] = (bf16)(acc[j] * dv);
    *(bf16x4*)gv = o;
  } else {
    bf16x8 o;
#pragma unroll
    for (int j = 0; j < 8; ++j) o[j] = (bf16)(acc[j] * dv);
    *(bf16x8*)gv = o;
  }
}

// ---------------- BatchNorm ----------------
template<int C>
__global__ __launch_bounds__(256) void k_stats(const bf16* __restrict__ g,
                                               float* __restrict__ sums, int N) {
  constexpr int CPT = C / 256;
  float s0[CPT], s1[CPT];
#pragma unroll
  for (int j = 0; j < CPT; ++j) { s0[j] = 0.f; s1[j] = 0.f; }
  for (int r = blockIdx.x; r < N; r += gridDim.x) {
    const bf16* row = g + (size_t)r * C;
#pragma unroll
    for (int j = 0; j < CPT; ++j) {
      float v = (float)row[threadIdx.x + j * 256];
      s0[j] += v; s1[j] += v * v;
    }
  }
#pragma unroll
  for (int j = 0; j < CPT; ++j) {
    atomicAdd(&sums[threadIdx.x + j * 256], s0[j]);
    atomicAdd(&sums[C + threadIdx.x + j * 256], s1[j]);
  }
}

__global__ void k_bnfinal(const float* __restrict__ sums, const float* __restrict__ gamma,
                          const float* __restrict__ beta, float* __restrict__ scale,
                          float* __restrict__ shift, int C, float invN) {
  int c = blockIdx.x * 256 + threadIdx.x;
  if (c >= C) return;
  float mu = sums[c] * invN;
  float var = sums[C + c] * invN - mu * mu;   // biased var (ddof=0)
  float is = rsqrtf(var + 1e-5f);
  float sc = gamma[c] * is;
  scale[c] = sc;
  shift[c] = beta[c] - mu * sc;
}

template<int C>
__global__ void k_bnapply(bf16* __restrict__ g, const float* __restrict__ scale,
                          const float* __restrict__ shift, int N, int Mp) {
  size_t base = ((size_t)blockIdx.x * 256 + threadIdx.x) * 4;
  if (base >= (size_t)Mp * C) return;
  int row = (int)(base / C);
  int col = (int)(base % C);
  bf16x4 o;
  if (row < N) {
    bf16x4 t = *(const bf16x4*)(g + base);
#pragma unroll
    for (int j = 0; j < 4; ++j)
      o[j] = (bf16)fmaxf(0.f, (float)t[j] * scale[col + j] + shift[col + j]);
  } else {
#pragma unroll
    for (int j = 0; j < 4; ++j) o[j] = (bf16)0.f;   // zero pad rows for next GEMM
  }
  *(bf16x4*)(g + base) = o;
}

// ---------------- launch ----------------
extern "C" void kernel_launch(void* const* d_in, const int* in_sizes, int n_in,
                              void* d_out, int out_size, void* d_ws, size_t ws_size,
                              hipStream_t stream) {
  const float* x   = (const float*)d_in[0];
  const int*   ei  = (const int*)d_in[1];
  const float* W1  = (const float*)d_in[2];
  // d_in[3] = b1: absorbed by BN (mean subtraction cancels it)
  const float* g1  = (const float*)d_in[4];
  const float* be1 = (const float*)d_in[5];
  const float* W2  = (const float*)d_in[6];
  // d_in[7] = b2: absorbed by BN
  const float* g2  = (const float*)d_in[8];
  const float* be2 = (const float*)d_in[9];
  const float* Wl  = (const float*)d_in[10];
  const float* bl  = (const float*)d_in[11];
  float* out = (float*)d_out;

  const int N  = in_sizes[0] / 128;          // 50000
  const int E  = in_sizes[1] / 2;            // 500000
  const int Mp = ((N + 127) / 128) * 128;    // 50048 = 391*128

  char* p = (char*)d_ws;
  auto carve = [&](size_t bytes) { void* r = (void*)p; p += (bytes + 255) & ~(size_t)255; return r; };
  int*   deg   = (int*)carve(sizeof(int) * N);
  int*   cur   = (int*)carve(sizeof(int) * N);
  int*   roff  = (int*)carve(sizeof(int) * (N + 1));
  int*   csr   = (int*)carve(sizeof(int) * E);
  float* dinv  = (float*)carve(sizeof(float) * N);
  float* sums1 = (float*)carve(sizeof(float) * 512);
  float* sums2 = (float*)carve(sizeof(float) * 1024);
  float* sc1   = (float*)carve(sizeof(float) * 256);
  float* sh1   = (float*)carve(sizeof(float) * 256);
  float* sc2   = (float*)carve(sizeof(float) * 512);
  float* sh2   = (float*)carve(sizeof(float) * 512);
  bf16*  xb    = (bf16*)carve(sizeof(bf16) * (size_t)Mp * 128);
  bf16*  w1t   = (bf16*)carve(sizeof(bf16) * 256 * 128);
  bf16*  w2t   = (bf16*)carve(sizeof(bf16) * 512 * 256);
  bf16*  wlt   = (bf16*)carve(sizeof(bf16) * 128 * 512);
  bf16*  h     = (bf16*)carve(sizeof(bf16) * (size_t)Mp * 512);  // shared h1/h2
  bf16*  a1    = (bf16*)carve(sizeof(bf16) * (size_t)Mp * 256);
  bf16*  a2    = (bf16*)carve(sizeof(bf16) * (size_t)Mp * 512);
  (void)n_in; (void)out_size; (void)ws_size;

  const int gN = (N + 255) / 256, gE = (E + 255) / 256;
  k_init<<<gN, 256, 0, stream>>>(deg, cur, sums1, sums2, N);
  k_count<<<gE, 256, 0, stream>>>(ei, deg, E);
  k_scan<<<1, 1024, 0, stream>>>(deg, roff, N);
  k_dinv<<<gN, 256, 0, stream>>>(deg, dinv, N);
  k_scatter<<<gE, 256, 0, stream>>>(ei, roff, cur, csr, E);

  k_cvt_x<<<(int)(((size_t)Mp * 128 / 4 + 255) / 256), 256, 0, stream>>>(x, xb, N, 128, (size_t)Mp * 128);
  k_cvt_wt<<<(128 * 256 + 255) / 256, 256, 0, stream>>>(W1, w1t, 128, 256);
  k_cvt_wt<<<(256 * 512 + 255) / 256, 256, 0, stream>>>(W2, w2t, 256, 512);
  k_cvt_wt<<<(512 * 128 + 255) / 256, 256, 0, stream>>>(Wl, wlt, 512, 128);

  // layer 1: h = xb @ W1 ; a1 = agg(h) ; BN+ReLU in place
  k_gemm<128, 256, false><<<dim3(Mp / 128, 2), 256, 0, stream>>>(xb, w1t, h, nullptr, nullptr, Mp);
  k_agg<256><<<(N + 3) / 4, 256, 0, stream>>>(h, a1, csr, roff, dinv, N);
  k_stats<256><<<256, 256, 0, stream>>>(a1, sums1, N);
  k_bnfinal<<<1, 256, 0, stream>>>(sums1, g1, be1, sc1, sh1, 256, 1.f / (float)N);
  k_bnapply<256><<<(int)(((size_t)Mp * 256 / 4 + 255) / 256), 256, 0, stream>>>(a1, sc1, sh1, N, Mp);

  // layer 2
  k_gemm<256, 512, false><<<dim3(Mp / 128, 4), 256, 0, stream>>>(a1, w2t, h, nullptr, nullptr, Mp);
  k_agg<512><<<(N + 3) / 4, 256, 0, stream>>>(h, a2, csr, roff, dinv, N);
  k_stats<512><<<256, 256, 0, stream>>>(a2, sums2, N);
  k_bnfinal<<<2, 256, 0, stream>>>(sums2, g2, be2, sc2, sh2, 512, 1.f / (float)N);
  k_bnapply<512><<<(int)(((size_t)Mp * 512 / 4 + 255) / 256), 256, 0, stream>>>(a2, sc2, sh2, N, Mp);

  // final linear: out = a2 @ Wl + bl (fp32 store, masked to real rows)
  k_gemm<512, 128, true><<<dim3(Mp / 128, 1), 256, 0, stream>>>(a2, wlt, nullptr, out, bl, N);
}

// Round 2
// 471.449 us; speedup vs baseline: 1.2741x; 1.2741x over previous
//
#include <hip/hip_runtime.h>
#include <cstdint>
#include <cstddef>

typedef __bf16 bf16;
typedef bf16 bf16x2 __attribute__((ext_vector_type(2)));
typedef bf16 bf16x4 __attribute__((ext_vector_type(4)));
typedef bf16 bf16x8 __attribute__((ext_vector_type(8)));
typedef float f32x4 __attribute__((ext_vector_type(4)));

// ---------------- graph preprocessing ----------------
__global__ void k_init(int* __restrict__ deg, int* __restrict__ cur,
                       float* __restrict__ sums1, float* __restrict__ sums2, int N) {
  int i = blockIdx.x * 256 + threadIdx.x;
  if (i < N) { deg[i] = 1; cur[i] = 0; }   // deg starts at 1: self loop
  if (i < 512)  sums1[i] = 0.f;
  if (i < 1024) sums2[i] = 0.f;
}

__global__ void k_count(const int* __restrict__ ei, int* __restrict__ deg, int E) {
  int e = blockIdx.x * 256 + threadIdx.x;
  if (e < E) atomicAdd(&deg[ei[E + e]], 1);   // dst = ei[E+e]
}

__global__ __launch_bounds__(1024) void k_scan(const int* __restrict__ deg,
                                               int* __restrict__ roff, int N) {
  __shared__ int part[1024];
  int t = threadIdx.x;
  int chunk = (N + 1023) >> 10;
  int lo = t * chunk, hi = min(lo + chunk, N);
  int s = 0;
  for (int i = lo; i < hi; ++i) s += deg[i] - 1;   // edge-only counts
  part[t] = s;
  __syncthreads();
  for (int off = 1; off < 1024; off <<= 1) {
    int add = (t >= off) ? part[t - off] : 0;
    __syncthreads();
    part[t] += add;
    __syncthreads();
  }
  int run = (t > 0) ? part[t - 1] : 0;
  for (int i = lo; i < hi; ++i) { roff[i] = run; run += deg[i] - 1; }
  if (t == 1023) roff[N] = part[1023];
}

__global__ void k_dinv(const int* __restrict__ deg, float* __restrict__ dinv, int N) {
  int i = blockIdx.x * 256 + threadIdx.x;
  if (i < N) dinv[i] = rsqrtf((float)deg[i]);
}

__global__ void k_scatter(const int* __restrict__ ei, const int* __restrict__ roff,
                          int* __restrict__ cur, int* __restrict__ csr, int E) {
  int e = blockIdx.x * 256 + threadIdx.x;
  if (e >= E) return;
  int d = ei[E + e];
  int p = atomicAdd(&cur[d], 1);
  csr[roff[d] + p] = ei[e];   // src
}

// ---------------- dtype conversion ----------------
__global__ void k_cvt_x(const float* __restrict__ x, bf16* __restrict__ xb, size_t total) {
  size_t base = ((size_t)blockIdx.x * 256 + threadIdx.x) * 4;
  if (base >= total) return;
  const float4 v = *(const float4*)(x + base);
  bf16x4 o;
  o[0] = (bf16)v.x; o[1] = (bf16)v.y; o[2] = (bf16)v.z; o[3] = (bf16)v.w;
  *(bf16x4*)(xb + base) = o;
}

// merged transpose+cast of all three weights: Wt[n][k] = W[k][n]
__global__ void k_cvt_w(const float* __restrict__ W1, const float* __restrict__ W2,
                        const float* __restrict__ Wl, bf16* __restrict__ w1t,
                        bf16* __restrict__ w2t, bf16* __restrict__ wlt) {
  int i = blockIdx.x * 256 + threadIdx.x;   // grid covers 229376 exactly
  if (i < 32768) {
    int n = i >> 7, k = i & 127;
    w1t[i] = (bf16)W1[(size_t)k * 256 + n];
  } else if (i < 163840) {
    int j = i - 32768;
    int n = j >> 8, k = j & 255;
    w2t[j] = (bf16)W2[(size_t)k * 512 + n];
  } else {
    int j = i - 163840;
    int n = j >> 9, k = j & 511;
    wlt[j] = (bf16)Wl[(size_t)k * 128 + n];
  }
}

// ---------------- bf16 MFMA GEMM: C[M,NOUT] = A[M,K] @ Bt[NOUT,K]^T ----------------
// 128x128 tile, BK=32, 4 waves computing 64x64 quadrants as 4x4 16x16 tiles.
// LDS: 16B slot s = kblock*128 + row; staged via global_load_lds width=16
// (dest = wave-uniform base + lane*16: s = it*256 + wv*64 + lane -> compatible).
// Non-FINAL: stores bf16 t + per-channel sum/sumsq atomics (BN stats fused).
template<int K, int NOUT, bool FINAL>
__global__ __launch_bounds__(256) void k_gemm(const bf16* __restrict__ A,
                                              const bf16* __restrict__ Bt,
                                              bf16* __restrict__ outB,
                                              float* __restrict__ outF,
                                              const float* __restrict__ bias,
                                              float* __restrict__ sums,
                                              int Mreal) {
  __shared__ uint4 lA[512];
  __shared__ uint4 lB[512];
  const int tid = threadIdx.x;
  const int wv = tid >> 6, lane = tid & 63;
  const int q = lane >> 4, mr = lane & 15;
  const int m0 = blockIdx.x * 128;
  const int n0 = blockIdx.y * 128;
  const int rw = (wv >> 1) * 64, cw = (wv & 1) * 64;
  f32x4 acc[4][4];
#pragma unroll
  for (int r = 0; r < 4; ++r)
#pragma unroll
    for (int c = 0; c < 4; ++c) acc[r][c] = (f32x4){0.f, 0.f, 0.f, 0.f};

  for (int k0 = 0; k0 < K; k0 += 32) {
    __syncthreads();
#pragma unroll
    for (int it = 0; it < 2; ++it) {
      int s = it * 256 + tid;
      int row = s & 127, kb = s >> 7;
      const bf16* ga = A + (size_t)(m0 + row) * K + (k0 + kb * 8);
      const bf16* gb = Bt + (size_t)(n0 + row) * K + (k0 + kb * 8);
      __builtin_amdgcn_global_load_lds((const __attribute__((address_space(1))) void*)ga,
                                       (__attribute__((address_space(3))) void*)(lA + s), 16, 0, 0);
      __builtin_amdgcn_global_load_lds((const __attribute__((address_space(1))) void*)gb,
                                       (__attribute__((address_space(3))) void*)(lB + s), 16, 0, 0);
    }
    __syncthreads();
    bf16x8 af[4], bfr[4];
#pragma unroll
    for (int r = 0; r < 4; ++r)
      af[r] = ((const bf16x8*)lA)[q * 128 + rw + r * 16 + mr];
#pragma unroll
    for (int c = 0; c < 4; ++c)
      bfr[c] = ((const bf16x8*)lB)[q * 128 + cw + c * 16 + mr];
#pragma unroll
    for (int r = 0; r < 4; ++r)
#pragma unroll
      for (int c = 0; c < 4; ++c)
        acc[r][c] = __builtin_amdgcn_mfma_f32_16x16x32_bf16(af[r], bfr[c], acc[r][c], 0, 0, 0);
  }

  // C/D layout: col = lane&15, row = (lane>>4)*4 + reg (m89/m91-verified)
#pragma unroll
  for (int c = 0; c < 4; ++c) {
    const int col = n0 + cw + c * 16 + mr;
    float s0 = 0.f, s1 = 0.f;
#pragma unroll
    for (int r = 0; r < 4; ++r) {
#pragma unroll
      for (int i = 0; i < 4; ++i) {
        int row = m0 + rw + r * 16 + q * 4 + i;
        float v = acc[r][c][i];
        if (FINAL) {
          if (row < Mreal) outF[(size_t)row * NOUT + col] = v + bias[col];
        } else {
          outB[(size_t)row * NOUT + col] = (bf16)v;
          if (row < Mreal) { s0 += v; s1 += v * v; }
        }
      }
    }
    if (!FINAL) {
      s0 += __shfl_xor(s0, 16, 64); s0 += __shfl_xor(s0, 32, 64);
      s1 += __shfl_xor(s1, 16, 64); s1 += __shfl_xor(s1, 32, 64);
      if (q == 0) { atomicAdd(&sums[col], s0); atomicAdd(&sums[NOUT + col], s1); }
    }
  }
}

// ---------------- CSR aggregation (one wave per node) ----------------
// g[v] = dinv[v] * ( sum_e dinv[s]*f(h[s]) + dinv[v]*f(h[v]) )
// where f = identity, or fused BN+ReLU of the previous layer (per-channel
// scale/shift held in registers: each lane owns fixed channels).
template<int C, bool BN>
__global__ __launch_bounds__(256) void k_agg(const bf16* __restrict__ h,
                                             bf16* __restrict__ g,
                                             const int* __restrict__ csr,
                                             const int* __restrict__ roff,
                                             const float* __restrict__ dinv,
                                             const float* __restrict__ scale,
                                             const float* __restrict__ shift,
                                             int N) {
  constexpr int VPL = C / 64;   // channels per lane: 2 or 4
  const int lane = threadIdx.x & 63;
  const int v = (int)(((unsigned)blockIdx.x * 256 + threadIdx.x) >> 6);
  if (v >= N) return;
  float sc[VPL], sh[VPL];
  if constexpr (BN) {
#pragma unroll
    for (int u = 0; u < VPL; ++u) { sc[u] = scale[lane * VPL + u]; sh[u] = shift[lane * VPL + u]; }
  }
  const float dv = dinv[v];
  float acc[VPL];
#pragma unroll
  for (int u = 0; u < VPL; ++u) acc[u] = 0.f;

  auto accum = [&](int src, float w) {
    const bf16* hr = h + (size_t)src * C + lane * VPL;
    float vals[VPL];
    if constexpr (VPL == 2) {
      bf16x2 t = *(const bf16x2*)hr;
      vals[0] = (float)t[0]; vals[1] = (float)t[1];
    } else {
      bf16x4 t = *(const bf16x4*)hr;
#pragma unroll
      for (int u = 0; u < 4; ++u) vals[u] = (float)t[u];
    }
#pragma unroll
    for (int u = 0; u < VPL; ++u) {
      float xx = vals[u];
      if constexpr (BN) xx = fmaxf(0.f, xx * sc[u] + sh[u]);
      acc[u] += w * xx;
    }
  };

  accum(v, dv);   // self loop (becomes dv^2 after final *dv)
  const int beg = roff[v], end = roff[v + 1];
  for (int base = beg; base < end; base += 64) {
    int cnt = min(64, end - base);
    int s = 0; float w = 0.f;
    if (lane < cnt) { s = csr[base + lane]; w = dinv[s]; }
    for (int j = 0; j < cnt; ++j) {
      int sj = __shfl(s, j, 64);
      float wj = __shfl(w, j, 64);
      accum(sj, wj);
    }
  }

  bf16* gv = g + (size_t)v * C + lane * VPL;
  if constexpr (VPL == 2) {
    bf16x2 o;
    o[0] = (bf16)(acc[0] * dv); o[1] = (bf16)(acc[1] * dv);
    *(bf16x2*)gv = o;
  } else {
    bf16x4 o;
#pragma unroll
    for (int u = 0; u < 4; ++u) o[u] = (bf16)(acc[u] * dv);
    *(bf16x4*)gv = o;
  }
}

// ---------------- BatchNorm ----------------
__global__ void k_bnfinal(const float* __restrict__ sums, const float* __restrict__ gamma,
                          const float* __restrict__ beta, float* __restrict__ scale,
                          float* __restrict__ shift, int C, float invN) {
  int c = blockIdx.x * 256 + threadIdx.x;
  if (c >= C) return;
  float mu = sums[c] * invN;
  float var = sums[C + c] * invN - mu * mu;   // biased var (ddof=0)
  float is = rsqrtf(var + 1e-5f);
  float sc = gamma[c] * is;
  scale[c] = sc;
  shift[c] = beta[c] - mu * sc;
}

// in-place BN+ReLU, 8-wide (pad rows processed too: finite garbage, masked downstream)
template<int C>
__global__ void k_bnapply(bf16* __restrict__ g, const float* __restrict__ scale,
                          const float* __restrict__ shift, size_t total) {
  size_t base = ((size_t)blockIdx.x * 256 + threadIdx.x) * 8;
  if (base >= total) return;
  int col = (int)(base & (size_t)(C - 1));
  bf16x8 t = *(const bf16x8*)(g + base);
  bf16x8 o;
#pragma unroll
  for (int j = 0; j < 8; ++j)
    o[j] = (bf16)fmaxf(0.f, (float)t[j] * scale[col + j] + shift[col + j]);
  *(bf16x8*)(g + base) = o;
}

// ---------------- launch ----------------
extern "C" void kernel_launch(void* const* d_in, const int* in_sizes, int n_in,
                              void* d_out, int out_size, void* d_ws, size_t ws_size,
                              hipStream_t stream) {
  const float* x   = (const float*)d_in[0];
  const int*   ei  = (const int*)d_in[1];
  const float* W1  = (const float*)d_in[2];
  // d_in[3] = b1: absorbed by BN (mean subtraction cancels it)
  const float* g1  = (const float*)d_in[4];
  const float* be1 = (const float*)d_in[5];
  const float* W2  = (const float*)d_in[6];
  // d_in[7] = b2: absorbed by BN
  const float* g2  = (const float*)d_in[8];
  const float* be2 = (const float*)d_in[9];
  const float* Wl  = (const float*)d_in[10];
  const float* bl  = (const float*)d_in[11];
  float* out = (float*)d_out;

  const int N  = in_sizes[0] / 128;          // 50000
  const int E  = in_sizes[1] / 2;            // 500000
  const int Mp = ((N + 127) / 128) * 128;    // 50048 = 391*128

  char* p = (char*)d_ws;
  auto carve = [&](size_t bytes) { void* r = (void*)p; p += (bytes + 255) & ~(size_t)255; return r; };
  int*   deg   = (int*)carve(sizeof(int) * N);
  int*   cur   = (int*)carve(sizeof(int) * N);
  int*   roff  = (int*)carve(sizeof(int) * (N + 1));
  int*   csr   = (int*)carve(sizeof(int) * E);
  float* dinv  = (float*)carve(sizeof(float) * N);
  float* sums1 = (float*)carve(sizeof(float) * 512);
  float* sums2 = (float*)carve(sizeof(float) * 1024);
  float* sc1   = (float*)carve(sizeof(float) * 256);
  float* sh1   = (float*)carve(sizeof(float) * 256);
  float* sc2   = (float*)carve(sizeof(float) * 512);
  float* sh2   = (float*)carve(sizeof(float) * 512);
  bf16*  w1t   = (bf16*)carve(sizeof(bf16) * 256 * 128);
  bf16*  w2t   = (bf16*)carve(sizeof(bf16) * 512 * 256);
  bf16*  wlt   = (bf16*)carve(sizeof(bf16) * 128 * 512);
  bf16*  xb    = (bf16*)carve(sizeof(bf16) * (size_t)Mp * 128);
  bf16*  ax1   = (bf16*)carve(sizeof(bf16) * (size_t)Mp * 128);  // agg(x)
  bf16*  t1    = (bf16*)carve(sizeof(bf16) * (size_t)Mp * 256);  // ax1 @ W1
  bf16*  ax2   = (bf16*)carve(sizeof(bf16) * (size_t)Mp * 256);  // agg(relu(bn(t1)))
  bf16*  t2    = (bf16*)carve(sizeof(bf16) * (size_t)Mp * 512);  // ax2 @ W2, then bn+relu in place
  (void)n_in; (void)out_size; (void)ws_size;

  const int gN = (N + 255) / 256, gE = (E + 255) / 256;
  k_init<<<gN, 256, 0, stream>>>(deg, cur, sums1, sums2, N);
  k_count<<<gE, 256, 0, stream>>>(ei, deg, E);
  k_scan<<<1, 1024, 0, stream>>>(deg, roff, N);
  k_dinv<<<gN, 256, 0, stream>>>(deg, dinv, N);
  k_scatter<<<gE, 256, 0, stream>>>(ei, roff, cur, csr, E);

  k_cvt_x<<<(int)(((size_t)N * 128 / 4 + 255) / 256), 256, 0, stream>>>(x, xb, (size_t)N * 128);
  k_cvt_w<<<896, 256, 0, stream>>>(W1, W2, Wl, w1t, w2t, wlt);

  const int gAgg = (N + 3) / 4;
  // layer 1: aggregate first (S commutes with dense transform), then GEMM(+stats)
  k_agg<128, false><<<gAgg, 256, 0, stream>>>(xb, ax1, csr, roff, dinv, nullptr, nullptr, N);
  k_gemm<128, 256, false><<<dim3(Mp / 128, 2), 256, 0, stream>>>(ax1, w1t, t1, nullptr, nullptr, sums1, N);
  k_bnfinal<<<1, 256, 0, stream>>>(sums1, g1, be1, sc1, sh1, 256, 1.f / (float)N);

  // layer 2: gather applies BN1+ReLU on the fly
  k_agg<256, true><<<gAgg, 256, 0, stream>>>(t1, ax2, csr, roff, dinv, sc1, sh1, N);
  k_gemm<256, 512, false><<<dim3(Mp / 128, 4), 256, 0, stream>>>(ax2, w2t, t2, nullptr, nullptr, sums2, N);
  k_bnfinal<<<2, 256, 0, stream>>>(sums2, g2, be2, sc2, sh2, 512, 1.f / (float)N);
  k_bnapply<512><<<(int)(((size_t)Mp * 512 / 8 + 255) / 256), 256, 0, stream>>>(t2, sc2, sh2, (size_t)Mp * 512);

  // final linear: out = a2 @ Wl + bl (fp32 store, masked to real rows)
  k_gemm<512, 128, true><<<dim3(Mp / 128, 1), 256, 0, stream>>>(t2, wlt, nullptr, out, bl, nullptr, N);
}

// Round 3
// 403.908 us; speedup vs baseline: 1.4871x; 1.1672x over previous
//
#include <hip/hip_runtime.h>
#include <cstdint>
#include <cstddef>

typedef __bf16 bf16;
typedef bf16 bf16x2 __attribute__((ext_vector_type(2)));
typedef bf16 bf16x4 __attribute__((ext_vector_type(4)));
typedef bf16 bf16x8 __attribute__((ext_vector_type(8)));
typedef float f32x4 __attribute__((ext_vector_type(4)));

// ---------------- graph preprocessing ----------------
__global__ void k_init(int* __restrict__ deg, int* __restrict__ cur,
                       float* __restrict__ sums1, float* __restrict__ sums2, int N) {
  int i = blockIdx.x * 256 + threadIdx.x;
  if (i < N) { deg[i] = 1; cur[i] = 0; }   // deg starts at 1: self loop
  if (i < 512)  sums1[i] = 0.f;
  if (i < 1024) sums2[i] = 0.f;
}

__global__ void k_count(const int* __restrict__ ei, int* __restrict__ deg, int E) {
  int e = blockIdx.x * 256 + threadIdx.x;
  if (e < E) atomicAdd(&deg[ei[E + e]], 1);   // dst = ei[E+e]
}

// hierarchical scan of (deg-1): scan1 block sums -> scan2 scans sums -> scan3 writes roff
__global__ __launch_bounds__(256) void k_scan1(const int* __restrict__ deg,
                                               int* __restrict__ bsum, int N) {
  int t = threadIdx.x;
  int i = blockIdx.x * 256 + t;
  int v = (i < N) ? deg[i] - 1 : 0;
#pragma unroll
  for (int off = 32; off > 0; off >>= 1) v += __shfl_down(v, off, 64);
  __shared__ int red[4];
  if ((t & 63) == 0) red[t >> 6] = v;
  __syncthreads();
  if (t == 0) bsum[blockIdx.x] = red[0] + red[1] + red[2] + red[3];
}

__global__ __launch_bounds__(256) void k_scan2(const int* __restrict__ bsum,
                                               int* __restrict__ bpre, int B) {
  __shared__ int s[256];
  int t = threadIdx.x;
  int v = (t < B) ? bsum[t] : 0;
  s[t] = v;
  __syncthreads();
  for (int off = 1; off < 256; off <<= 1) {
    int add = (t >= off) ? s[t - off] : 0;
    __syncthreads();
    s[t] += add;
    __syncthreads();
  }
  if (t < B) bpre[t] = s[t] - v;   // exclusive
}

__global__ __launch_bounds__(256) void k_scan3(const int* __restrict__ deg,
                                               const int* __restrict__ bpre,
                                               int* __restrict__ roff,
                                               float* __restrict__ dinv, int N) {
  __shared__ int s[256];
  int t = threadIdx.x;
  int i = blockIdx.x * 256 + t;
  int d = (i < N) ? deg[i] : 1;
  int v = d - 1;
  if (i >= N) v = 0;
  s[t] = v;
  __syncthreads();
  for (int off = 1; off < 256; off <<= 1) {
    int add = (t >= off) ? s[t - off] : 0;
    __syncthreads();
    s[t] += add;
    __syncthreads();
  }
  if (i < N) {
    int base = bpre[blockIdx.x];
    roff[i] = base + s[t] - v;
    dinv[i] = rsqrtf((float)d);
    if (i == N - 1) roff[N] = base + s[t];
  }
}

__global__ void k_scatter(const int* __restrict__ ei, const int* __restrict__ roff,
                          int* __restrict__ cur, int* __restrict__ csr, int E) {
  int e = blockIdx.x * 256 + threadIdx.x;
  if (e >= E) return;
  int d = ei[E + e];
  int p = atomicAdd(&cur[d], 1);
  csr[roff[d] + p] = ei[e];   // src
}

// ---------------- dtype conversion ----------------
__global__ void k_cvt_x(const float* __restrict__ x, bf16* __restrict__ xb, size_t total) {
  size_t base = ((size_t)blockIdx.x * 256 + threadIdx.x) * 4;
  if (base >= total) return;
  const float4 v = *(const float4*)(x + base);
  bf16x4 o;
  o[0] = (bf16)v.x; o[1] = (bf16)v.y; o[2] = (bf16)v.z; o[3] = (bf16)v.w;
  *(bf16x4*)(xb + base) = o;
}

// merged transpose+cast of all three weights: Wt[n][k] = W[k][n]
__global__ void k_cvt_w(const float* __restrict__ W1, const float* __restrict__ W2,
                        const float* __restrict__ Wl, bf16* __restrict__ w1t,
                        bf16* __restrict__ w2t, bf16* __restrict__ wlt) {
  int i = blockIdx.x * 256 + threadIdx.x;   // grid covers 229376 exactly
  if (i < 32768) {
    int n = i >> 7, k = i & 127;
    w1t[i] = (bf16)W1[(size_t)k * 256 + n];
  } else if (i < 163840) {
    int j = i - 32768;
    int n = j >> 8, k = j & 255;
    w2t[j] = (bf16)W2[(size_t)k * 512 + n];
  } else {
    int j = i - 163840;
    int n = j >> 9, k = j & 511;
    wlt[j] = (bf16)Wl[(size_t)k * 128 + n];
  }
}

// ---------------- bf16 MFMA GEMM: C[M,NOUT] = A[M,K] @ Bt[NOUT,K]^T ----------------
// 128x128 tile, BK=32, 4 waves computing 64x64 quadrants as 4x4 16x16 tiles.
// LDS: 16B slot s = kblock*128 + row; staged via global_load_lds width=16
// (dest = wave-uniform base + lane*16: s = it*256 + wv*64 + lane -> compatible).
// Non-FINAL: stores bf16 t + per-channel sum/sumsq atomics (BN stats fused).
template<int K, int NOUT, bool FINAL>
__global__ __launch_bounds__(256) void k_gemm(const bf16* __restrict__ A,
                                              const bf16* __restrict__ Bt,
                                              bf16* __restrict__ outB,
                                              float* __restrict__ outF,
                                              const float* __restrict__ bias,
                                              float* __restrict__ sums,
                                              int Mreal) {
  __shared__ uint4 lA[512];
  __shared__ uint4 lB[512];
  const int tid = threadIdx.x;
  const int wv = tid >> 6, lane = tid & 63;
  const int q = lane >> 4, mr = lane & 15;
  const int m0 = blockIdx.x * 128;
  const int n0 = blockIdx.y * 128;
  const int rw = (wv >> 1) * 64, cw = (wv & 1) * 64;
  f32x4 acc[4][4];
#pragma unroll
  for (int r = 0; r < 4; ++r)
#pragma unroll
    for (int c = 0; c < 4; ++c) acc[r][c] = (f32x4){0.f, 0.f, 0.f, 0.f};

  for (int k0 = 0; k0 < K; k0 += 32) {
    __syncthreads();
#pragma unroll
    for (int it = 0; it < 2; ++it) {
      int s = it * 256 + tid;
      int row = s & 127, kb = s >> 7;
      const bf16* ga = A + (size_t)(m0 + row) * K + (k0 + kb * 8);
      const bf16* gb = Bt + (size_t)(n0 + row) * K + (k0 + kb * 8);
      __builtin_amdgcn_global_load_lds((const __attribute__((address_space(1))) void*)ga,
                                       (__attribute__((address_space(3))) void*)(lA + s), 16, 0, 0);
      __builtin_amdgcn_global_load_lds((const __attribute__((address_space(1))) void*)gb,
                                       (__attribute__((address_space(3))) void*)(lB + s), 16, 0, 0);
    }
    __syncthreads();
    bf16x8 af[4], bfr[4];
#pragma unroll
    for (int r = 0; r < 4; ++r)
      af[r] = ((const bf16x8*)lA)[q * 128 + rw + r * 16 + mr];
#pragma unroll
    for (int c = 0; c < 4; ++c)
      bfr[c] = ((const bf16x8*)lB)[q * 128 + cw + c * 16 + mr];
#pragma unroll
    for (int r = 0; r < 4; ++r)
#pragma unroll
      for (int c = 0; c < 4; ++c)
        acc[r][c] = __builtin_amdgcn_mfma_f32_16x16x32_bf16(af[r], bfr[c], acc[r][c], 0, 0, 0);
  }

  // C/D layout: col = lane&15, row = (lane>>4)*4 + reg (m89/m91-verified)
#pragma unroll
  for (int c = 0; c < 4; ++c) {
    const int col = n0 + cw + c * 16 + mr;
    float s0 = 0.f, s1 = 0.f;
#pragma unroll
    for (int r = 0; r < 4; ++r) {
#pragma unroll
      for (int i = 0; i < 4; ++i) {
        int row = m0 + rw + r * 16 + q * 4 + i;
        float v = acc[r][c][i];
        if (FINAL) {
          if (row < Mreal) outF[(size_t)row * NOUT + col] = v + bias[col];
        } else {
          outB[(size_t)row * NOUT + col] = (bf16)v;
          if (row < Mreal) { s0 += v; s1 += v * v; }
        }
      }
    }
    if (!FINAL) {
      s0 += __shfl_xor(s0, 16, 64); s0 += __shfl_xor(s0, 32, 64);
      s1 += __shfl_xor(s1, 16, 64); s1 += __shfl_xor(s1, 32, 64);
      if (q == 0) { atomicAdd(&sums[col], s0); atomicAdd(&sums[NOUT + col], s1); }
    }
  }
}

// ---------------- CSR aggregation (one wave per node) ----------------
// g[v] = dinv[v] * ( sum_e dinv[s]*f(h[s]) + dinv[v]*f(h[v]) )
// where f = identity, or fused BN+ReLU of the previous layer (per-channel
// scale/shift held in registers: each lane owns fixed channels).
template<int C, bool BN>
__global__ __launch_bounds__(256) void k_agg(const bf16* __restrict__ h,
                                             bf16* __restrict__ g,
                                             const int* __restrict__ csr,
                                             const int* __restrict__ roff,
                                             const float* __restrict__ dinv,
                                             const float* __restrict__ scale,
                                             const float* __restrict__ shift,
                                             int N) {
  constexpr int VPL = C / 64;   // channels per lane: 2 or 4
  const int lane = threadIdx.x & 63;
  const int v = (int)(((unsigned)blockIdx.x * 256 + threadIdx.x) >> 6);
  if (v >= N) return;
  float sc[VPL], sh[VPL];
  if constexpr (BN) {
#pragma unroll
    for (int u = 0; u < VPL; ++u) { sc[u] = scale[lane * VPL + u]; sh[u] = shift[lane * VPL + u]; }
  }
  const float dv = dinv[v];
  float acc[VPL];
#pragma unroll
  for (int u = 0; u < VPL; ++u) acc[u] = 0.f;

  auto accum = [&](int src, float w) {
    const bf16* hr = h + (size_t)src * C + lane * VPL;
    float vals[VPL];
    if constexpr (VPL == 2) {
      bf16x2 t = *(const bf16x2*)hr;
      vals[0] = (float)t[0]; vals[1] = (float)t[1];
    } else {
      bf16x4 t = *(const bf16x4*)hr;
#pragma unroll
      for (int u = 0; u < 4; ++u) vals[u] = (float)t[u];
    }
#pragma unroll
    for (int u = 0; u < VPL; ++u) {
      float xx = vals[u];
      if constexpr (BN) xx = fmaxf(0.f, xx * sc[u] + sh[u]);
      acc[u] += w * xx;
    }
  };

  accum(v, dv);   // self loop (becomes dv^2 after final *dv)
  const int beg = roff[v], end = roff[v + 1];
  for (int base = beg; base < end; base += 64) {
    int cnt = min(64, end - base);
    int s = 0; float w = 0.f;
    if (lane < cnt) { s = csr[base + lane]; w = dinv[s]; }
    for (int j = 0; j < cnt; ++j) {
      int sj = __shfl(s, j, 64);
      float wj = __shfl(w, j, 64);
      accum(sj, wj);
    }
  }

  bf16* gv = g + (size_t)v * C + lane * VPL;
  if constexpr (VPL == 2) {
    bf16x2 o;
    o[0] = (bf16)(acc[0] * dv); o[1] = (bf16)(acc[1] * dv);
    *(bf16x2*)gv = o;
  } else {
    bf16x4 o;
#pragma unroll
    for (int u = 0; u < 4; ++u) o[u] = (bf16)(acc[u] * dv);
    *(bf16x4*)gv = o;
  }
}

// ---------------- BatchNorm ----------------
__global__ void k_bnfinal(const float* __restrict__ sums, const float* __restrict__ gamma,
                          const float* __restrict__ beta, float* __restrict__ scale,
                          float* __restrict__ shift, int C, float invN) {
  int c = blockIdx.x * 256 + threadIdx.x;
  if (c >= C) return;
  float mu = sums[c] * invN;
  float var = sums[C + c] * invN - mu * mu;   // biased var (ddof=0)
  float is = rsqrtf(var + 1e-5f);
  float sc = gamma[c] * is;
  scale[c] = sc;
  shift[c] = beta[c] - mu * sc;
}

// in-place BN+ReLU, 8-wide (pad rows processed too: finite garbage, masked downstream)
template<int C>
__global__ void k_bnapply(bf16* __restrict__ g, const float* __restrict__ scale,
                          const float* __restrict__ shift, size_t total) {
  size_t base = ((size_t)blockIdx.x * 256 + threadIdx.x) * 8;
  if (base >= total) return;
  int col = (int)(base & (size_t)(C - 1));
  bf16x8 t = *(const bf16x8*)(g + base);
  bf16x8 o;
#pragma unroll
  for (int j = 0; j < 8; ++j)
    o[j] = (bf16)fmaxf(0.f, (float)t[j] * scale[col + j] + shift[col + j]);
  *(bf16x8*)(g + base) = o;
}

// ---------------- launch ----------------
extern "C" void kernel_launch(void* const* d_in, const int* in_sizes, int n_in,
                              void* d_out, int out_size, void* d_ws, size_t ws_size,
                              hipStream_t stream) {
  const float* x   = (const float*)d_in[0];
  const int*   ei  = (const int*)d_in[1];
  const float* W1  = (const float*)d_in[2];
  // d_in[3] = b1: absorbed by BN (mean subtraction cancels it)
  const float* g1  = (const float*)d_in[4];
  const float* be1 = (const float*)d_in[5];
  const float* W2  = (const float*)d_in[6];
  // d_in[7] = b2: absorbed by BN
  const float* g2  = (const float*)d_in[8];
  const float* be2 = (const float*)d_in[9];
  const float* Wl  = (const float*)d_in[10];
  const float* bl  = (const float*)d_in[11];
  float* out = (float*)d_out;

  const int N  = in_sizes[0] / 128;          // 50000
  const int E  = in_sizes[1] / 2;            // 500000
  const int Mp = ((N + 127) / 128) * 128;    // 50048 = 391*128
  const int NB = (N + 255) / 256;            // scan blocks (196)

  char* p = (char*)d_ws;
  auto carve = [&](size_t bytes) { void* r = (void*)p; p += (bytes + 255) & ~(size_t)255; return r; };
  int*   deg   = (int*)carve(sizeof(int) * N);
  int*   cur   = (int*)carve(sizeof(int) * N);
  int*   roff  = (int*)carve(sizeof(int) * (N + 1));
  int*   csr   = (int*)carve(sizeof(int) * E);
  int*   bsum  = (int*)carve(sizeof(int) * 256);
  int*   bpre  = (int*)carve(sizeof(int) * 256);
  float* dinv  = (float*)carve(sizeof(float) * N);
  float* sums1 = (float*)carve(sizeof(float) * 512);
  float* sums2 = (float*)carve(sizeof(float) * 1024);
  float* sc1   = (float*)carve(sizeof(float) * 256);
  float* sh1   = (float*)carve(sizeof(float) * 256);
  float* sc2   = (float*)carve(sizeof(float) * 512);
  float* sh2   = (float*)carve(sizeof(float) * 512);
  bf16*  w1t   = (bf16*)carve(sizeof(bf16) * 256 * 128);
  bf16*  w2t   = (bf16*)carve(sizeof(bf16) * 512 * 256);
  bf16*  wlt   = (bf16*)carve(sizeof(bf16) * 128 * 512);
  bf16*  xb    = (bf16*)carve(sizeof(bf16) * (size_t)Mp * 128);
  bf16*  ax1   = (bf16*)carve(sizeof(bf16) * (size_t)Mp * 128);  // agg(x)
  bf16*  t1    = (bf16*)carve(sizeof(bf16) * (size_t)Mp * 256);  // ax1 @ W1
  bf16*  ax2   = (bf16*)carve(sizeof(bf16) * (size_t)Mp * 256);  // agg(relu(bn(t1)))
  bf16*  t2    = (bf16*)carve(sizeof(bf16) * (size_t)Mp * 512);  // ax2 @ W2, then bn+relu in place
  (void)n_in; (void)out_size; (void)ws_size;

  const int gE = (E + 255) / 256;
  k_init<<<NB, 256, 0, stream>>>(deg, cur, sums1, sums2, N);
  k_count<<<gE, 256, 0, stream>>>(ei, deg, E);
  k_scan1<<<NB, 256, 0, stream>>>(deg, bsum, N);
  k_scan2<<<1, 256, 0, stream>>>(bsum, bpre, NB);
  k_scan3<<<NB, 256, 0, stream>>>(deg, bpre, roff, dinv, N);   // dinv fused
  k_scatter<<<gE, 256, 0, stream>>>(ei, roff, cur, csr, E);

  k_cvt_x<<<(int)(((size_t)N * 128 / 4 + 255) / 256), 256, 0, stream>>>(x, xb, (size_t)N * 128);
  k_cvt_w<<<896, 256, 0, stream>>>(W1, W2, Wl, w1t, w2t, wlt);

  const int gAgg = (N + 3) / 4;
  // layer 1: aggregate first (S commutes with dense transform), then GEMM(+stats)
  k_agg<128, false><<<gAgg, 256, 0, stream>>>(xb, ax1, csr, roff, dinv, nullptr, nullptr, N);
  k_gemm<128, 256, false><<<dim3(Mp / 128, 2), 256, 0, stream>>>(ax1, w1t, t1, nullptr, nullptr, sums1, N);
  k_bnfinal<<<1, 256, 0, stream>>>(sums1, g1, be1, sc1, sh1, 256, 1.f / (float)N);

  // layer 2: gather applies BN1+ReLU on the fly
  k_agg<256, true><<<gAgg, 256, 0, stream>>>(t1, ax2, csr, roff, dinv, sc1, sh1, N);
  k_gemm<256, 512, false><<<dim3(Mp / 128, 4), 256, 0, stream>>>(ax2, w2t, t2, nullptr, nullptr, sums2, N);
  k_bnfinal<<<2, 256, 0, stream>>>(sums2, g2, be2, sc2, sh2, 512, 1.f / (float)N);
  k_bnapply<512><<<(int)(((size_t)Mp * 512 / 8 + 255) / 256), 256, 0, stream>>>(t2, sc2, sh2, (size_t)Mp * 512);

  // final linear: out = a2 @ Wl + bl (fp32 store, masked to real rows)
  k_gemm<512, 128, true><<<dim3(Mp / 128, 1), 256, 0, stream>>>(t2, wlt, nullptr, out, bl, nullptr, N);
}